// Round 1
// baseline (178.133 us; speedup 1.0000x reference)
//
#include <hip/hip_runtime.h>

// LIF neuron forward scan.
// x_seq: (T=64, B=32, F=8192) fp32. Outputs: spike_seq then mem_seq, same shape,
// concatenated flat in d_out.
//
// Recurrence per (b,f):
//   mem = mem * 0.5 + x          (tau_mem=2 -> 1-decay = 0.5; dt=1)
//   spike = (mem >= 1.0) ? 1 : 0
//   mem = spike ? 0 : mem        (v_reset = 0)
//
// Memory-bound: 201 MiB total traffic -> ~32 us floor at 6.3 TB/s.
//
// R3 changes vs R2 (float2 + nt loads + nt stores, 176 us):
//  - float4 per thread (16 B/lane = coalescing sweet spot, 1 KiB/wave-instr);
//    halves VMEM instruction count and vmcnt queue pressure.
//  - CACHED loads for x (drop nontemporal): x is 67 MB, re-read every timed
//    iteration, fits L3; nt-loads mark it evict-first and forfeit residency.
//  - Keep nontemporal STORES: outputs are never re-read by the kernel;
//    streaming them avoids evicting x from L2/L3.
//  - unroll 8 retained: 8 KiB loads in flight/wave, 32 KiB/CU at 4 waves/CU,
//    ~10x the in-flight bytes needed to cover ~900 cy HBM latency.

#define T_STEPS 64
#define BF (32 * 8192)          // 262144 elements per timestep
#define BF4 (BF / 4)            // 65536 float4 groups per timestep

typedef float v4f __attribute__((ext_vector_type(4)));

__global__ __launch_bounds__(256) void lif_fwd_kernel(
    const v4f* __restrict__ x,        // T * BF4
    v4f* __restrict__ spike_out,      // T * BF4
    v4f* __restrict__ mem_out)        // T * BF4
{
    const int idx = blockIdx.x * blockDim.x + threadIdx.x;  // 0 .. BF4-1

    v4f mem = {0.f, 0.f, 0.f, 0.f};

#pragma unroll 8
    for (int t = 0; t < T_STEPS; ++t) {
        const v4f xv = x[t * BF4 + idx];   // cached load (L3-friendly)

        v4f sp;
#pragma unroll
        for (int j = 0; j < 4; ++j) {
            const float m = fmaf(mem[j], 0.5f, xv[j]);
            const bool s = (m >= 1.0f);
            sp[j]  = s ? 1.0f : 0.0f;
            mem[j] = s ? 0.0f : m;
        }

        __builtin_nontemporal_store(sp,  &spike_out[t * BF4 + idx]);
        __builtin_nontemporal_store(mem, &mem_out[t * BF4 + idx]);
    }
}

extern "C" void kernel_launch(void* const* d_in, const int* in_sizes, int n_in,
                              void* d_out, int out_size, void* d_ws, size_t ws_size,
                              hipStream_t stream) {
    const v4f* x = (const v4f*)d_in[0];
    v4f* spike_out = (v4f*)d_out;                              // first T*BF floats
    v4f* mem_out   = (v4f*)d_out + (size_t)T_STEPS * BF4;      // second half

    lif_fwd_kernel<<<BF4 / 256, 256, 0, stream>>>(x, spike_out, mem_out);
}